// Round 17
// baseline (97.495 us; speedup 1.0000x reference)
//
#include <hip/hip_runtime.h>
#include <stdint.h>

#define NQ 10
#define DIMQ 1024
#define BATCH 4096

typedef float f32x2 __attribute__((ext_vector_type(2)));

#if __has_builtin(__builtin_amdgcn_permlane16_swap)
#define HAS_PL16 1
#else
#define HAS_PL16 0
#endif

// Layer's 10 CNOTs composed as a GF(2)-linear index map (scatter form).
__host__ __device__ constexpr int cperm_c(int x, int r) {
  for (int q = 0; q < NQ; ++q) {
    const int c = 9 - q;
    int t = c - r; if (t < 0) t += NQ;
    x ^= ((x >> c) & 1) << t;
  }
  return x;
}
// Epilogue sign masks (layer-3 perm r=4 folded into signs).
constexpr int amask(int q) {
  int a = 0;
  for (int b = 0; b < 6; ++b) a |= ((cperm_c(1 << b, 4) >> (9 - q)) & 1) << b;
  return a;
}
constexpr int mmask(int q) {
  int m = 0;
  for (int b = 0; b < 4; ++b) m |= ((cperm_c(1 << (6 + b), 4) >> (9 - q)) & 1) << b;
  return m;
}

// ------------------------------------------------------- gate precompute ---
// Per gate: float4 (c, s, t, 0), t = tan(theta/2) for the 3-shear reg gates
// (R16-proven). E tables pre-packed float4 {c, c, -s, s} (R15-proven).
__global__ __launch_bounds__(256) void prep_g(const float* __restrict__ wts,
                                              float* __restrict__ Gg) {
  const int idx = blockIdx.x * 256 + threadIdx.x;   // grid 4 x 256 = 1024
  if (idx < 40) {
    float th = wts[idx * 3 + 1];
    ((float4*)Gg)[idx] = make_float4(cosf(0.5f * th), sinf(0.5f * th),
                                     tanf(0.25f * th), 0.f);
  }
  f32x2* D0 = (f32x2*)(Gg + 256);
  float4* E = (float4*)(D0 + 1024);     // E0, E1, E2 consecutive (1024 each)
  auto sphase = [&](int l, int i, int comp) {   // comp: 0=phi, 2=omega
    float s = 0.f;
    #pragma unroll
    for (int q = 0; q < 10; ++q) {              // wts loads are uniform
      float sg = ((i >> (9 - q)) & 1) ? 0.5f : -0.5f;
      s += sg * wts[(l * 10 + q) * 3 + comp];
    }
    return s;
  };
  float p0 = sphase(0, idx, 0);
  D0[idx] = (f32x2){cosf(p0), sinf(p0)};
  #pragma unroll
  for (int l = 0; l < 3; ++l) {
    float a = sphase(l, idx, 2) + sphase(l + 1, cperm_c(idx, l + 1), 0);
    E[l * 1024 + idx] = make_float4(cosf(a), cosf(a), -sinf(a), sinf(a));
  }
}

// ---- VALU-pipe lane shuffles ----
template<int CTRL>
__device__ __forceinline__ float dpp1(float x) {
  return __int_as_float(
      __builtin_amdgcn_update_dpp(0, __float_as_int(x), CTRL, 0xF, 0xF, true));
}
// quad_perm xor1=0xB1, xor2=0x4E, xor3=0x1B; row_half_mirror(^7)=0x141;
// row_ror:8 = 0x128 == ^8. ^4 = ^7 o ^3 (double DPP — R17: back off the DS
// pipe so cross-row scheduling has pure-VALU work to interleave).
template<int P>   // P = lane bit, 0..3
__device__ __forceinline__ float shufl(float x) {
  if constexpr (P == 0)      return dpp1<0xB1>(x);
  else if constexpr (P == 1) return dpp1<0x4E>(x);
  else if constexpr (P == 2) return dpp1<0x141>(dpp1<0x1B>(x));
  else                       return dpp1<0x128>(x);   // row_ror:8 == ^8
}

__device__ __forceinline__ f32x2 swapv(f32x2 v) {
  return __builtin_shufflevector(v, v, 1, 0);
}

// Wave sum -> uniform scalar.
__device__ __forceinline__ float red64(float v) {
  v += dpp1<0xB1>(v);
  v += dpp1<0x4E>(v);
  v += dpp1<0x141>(dpp1<0x1B>(v));   // ^4
  v += dpp1<0x128>(v);               // ^8 (row_ror:8)
#if HAS_PL16
  { auto rr = __builtin_amdgcn_permlane16_swap(__float_as_uint(v),
                                               __float_as_uint(v), false, false);
    v = __uint_as_float(rr[0]) + __uint_as_float(rr[1]); }
#else
  v += __int_as_float(__builtin_amdgcn_ds_swizzle(__float_as_int(v), 0x401F));
#endif
  auto p = __builtin_amdgcn_permlane32_swap(__float_as_uint(v),
                                            __float_as_uint(v), false, false);
  return __uint_as_float(p[0]) + __uint_as_float(p[1]);
}

// ---- REAL Givens rotations over TWO rows (s[0..15]=A, s[16..31]=B) ----
// Reg-bit gate in 3-shear (lifting) form, R16-proven.
template<int MT>
__device__ __forceinline__ void ry_reg(f32x2 (&s)[32], float t, float sn) {
  #pragma unroll
  for (int g = 0; g < 32; g += 16)
    #pragma unroll
    for (int e0 = 0; e0 < 16; ++e0) {
      if (e0 & MT) continue;
      const int i0 = g + e0, i1 = g + (e0 | MT);
      s[i0] = s[i0] - t * s[i1];
      s[i1] = s[i1] + sn * s[i0];
      s[i0] = s[i0] - t * s[i1];
    }
}
template<int P>    // lane bits 0..3 via DPP
__device__ __forceinline__ void ry_dpp(f32x2 (&s)[32], float2 cs, int lane) {
  const float c = cs.x;
  const float ss = ((lane >> P) & 1) ? cs.y : -cs.y;
  #pragma unroll
  for (int i = 0; i < 32; ++i) {
    f32x2 o;
    o.x = shufl<P>(s[i].x);
    o.y = shufl<P>(s[i].y);
    s[i] = c * s[i] + ss * o;
  }
}
// lane bit 4 (xor16): select-free permlane16_swap (R15-proven).
__device__ __forceinline__ void ry16(f32x2 (&s)[32], float2 cs, int lane) {
  const bool H = (lane & 16) != 0;
#if HAS_PL16
  const float b0 = H ? cs.y : 0.f;
  const float b1 = H ? 0.f : -cs.y;
  const float c = cs.x;
  #pragma unroll
  for (int i = 0; i < 32; ++i) {
    auto rr = __builtin_amdgcn_permlane16_swap(__float_as_uint(s[i].x),
                                               __float_as_uint(s[i].x), false, false);
    auto ri = __builtin_amdgcn_permlane16_swap(__float_as_uint(s[i].y),
                                               __float_as_uint(s[i].y), false, false);
    f32x2 o0, o1;
    o0.x = __uint_as_float(rr[0]); o0.y = __uint_as_float(ri[0]);
    o1.x = __uint_as_float(rr[1]); o1.y = __uint_as_float(ri[1]);
    s[i] = c * s[i] + b0 * o0 + b1 * o1;
  }
#else
  const float c = cs.x;
  const float ss = H ? cs.y : -cs.y;
  #pragma unroll
  for (int i = 0; i < 32; ++i) {
    f32x2 o;
    o.x = __int_as_float(__builtin_amdgcn_ds_swizzle(__float_as_int(s[i].x), 0x401F));
    o.y = __int_as_float(__builtin_amdgcn_ds_swizzle(__float_as_int(s[i].y), 0x401F));
    s[i] = c * s[i] + ss * o;
  }
#endif
}
// lane bit 5 (xor32): select-free permlane32_swap (R15-proven).
__device__ __forceinline__ void ry5(f32x2 (&s)[32], float2 cs, int lane) {
  const int L = lane >> 5;
  const float c = cs.x;
  const float a0 = L ? cs.y : 0.f;
  const float a1 = L ? 0.f : -cs.y;
  #pragma unroll
  for (int i = 0; i < 32; ++i) {
    auto rr = __builtin_amdgcn_permlane32_swap(__float_as_uint(s[i].x),
                                               __float_as_uint(s[i].x), false, false);
    auto ri = __builtin_amdgcn_permlane32_swap(__float_as_uint(s[i].y),
                                               __float_as_uint(s[i].y), false, false);
    f32x2 o0, o1;
    o0.x = __uint_as_float(rr[0]); o0.y = __uint_as_float(ri[0]);
    o1.x = __uint_as_float(rr[1]); o1.y = __uint_as_float(ri[1]);
    s[i] = c * s[i] + a0 * o0 + a1 * o1;
  }
}

// CNOT permutation: each row via its own private LDS slice (same-wave DS
// in-order, no barrier). Row-A round trip issued first; row-B scatter
// overlaps row-A's gather latency.
template<int R>
__device__ __forceinline__ void perm2(f32x2 (&s)[32], f32x2* __restrict__ L0,
                                      f32x2* __restrict__ L1, int lane) {
  constexpr int K0=cperm_c(1,R),  K1=cperm_c(2,R),  K2=cperm_c(4,R),
                K3=cperm_c(8,R),  K4=cperm_c(16,R), K5=cperm_c(32,R),
                C6=cperm_c(64,R), C7=cperm_c(128,R),
                C8=cperm_c(256,R),C9=cperm_c(512,R);
  const int yl = ((lane & 1)  ? K0 : 0) ^ ((lane & 2)  ? K1 : 0) ^
                 ((lane & 4)  ? K2 : 0) ^ ((lane & 8)  ? K3 : 0) ^
                 ((lane & 16) ? K4 : 0) ^ ((lane & 32) ? K5 : 0);
  #pragma unroll
  for (int e = 0; e < 16; ++e) {
    const int ye = ((e & 1) ? C6 : 0) ^ ((e & 2) ? C7 : 0) ^
                   ((e & 4) ? C8 : 0) ^ ((e & 8) ? C9 : 0);
    L0[yl ^ ye] = s[e];
  }
  #pragma unroll
  for (int e = 0; e < 16; ++e) s[e] = L0[(e << 6) | lane];
  #pragma unroll
  for (int e = 0; e < 16; ++e) {
    const int ye = ((e & 1) ? C6 : 0) ^ ((e & 2) ? C7 : 0) ^
                   ((e & 4) ? C8 : 0) ^ ((e & 8) ? C9 : 0);
    L1[yl ^ ye] = s[16 + e];
  }
  #pragma unroll
  for (int e = 0; e < 16; ++e) s[16 + e] = L1[(e << 6) | lane];
}

template<int LYR>
__device__ __forceinline__ void do_layer(f32x2 (&s)[32],
                                         const float4* __restrict__ gq,
                                         const float4* __restrict__ Etab,
                                         f32x2* __restrict__ L0,
                                         f32x2* __restrict__ L1, int lane) {
  // E-prefetch first (SHARED between the two rows — same (e,lane) indices).
  float4 et[16];
  if constexpr (LYR < 3) {
    const float4* El = Etab + LYR * 1024;
    #pragma unroll
    for (int e = 0; e < 16; ++e) et[e] = El[(e << 6) | lane];
  }
  const float4* G = gq + LYR * 10;
  ry_reg<8>(s, G[0].z, G[0].y);          // q0 -> bit9 (3-shear)
  ry_reg<4>(s, G[1].z, G[1].y);          // q1 -> bit8
  ry_reg<2>(s, G[2].z, G[2].y);          // q2 -> bit7
  ry_reg<1>(s, G[3].z, G[3].y);          // q3 -> bit6
  ry5     (s, make_float2(G[4].x, G[4].y), lane);  // q4 -> bit5 (permlane32)
  ry16    (s, make_float2(G[5].x, G[5].y), lane);  // q5 -> bit4 (permlane16)
  ry_dpp<3>(s, make_float2(G[6].x, G[6].y), lane); // q6 -> bit3 (row_ror:8)
  ry_dpp<2>(s, make_float2(G[7].x, G[7].y), lane); // q7 -> bit2 (double DPP)
  ry_dpp<1>(s, make_float2(G[8].x, G[8].y), lane); // q8 -> bit1 (DPP)
  ry_dpp<0>(s, make_float2(G[9].x, G[9].y), lane); // q9 -> bit0 (DPP)
  if constexpr (LYR < 3) {
    #pragma unroll
    for (int i = 0; i < 32; ++i) {       // merged diag: 2 packed ops, shared et
      f32x2 e1; e1.x = et[i & 15].x; e1.y = et[i & 15].y;   // (c, c)
      f32x2 e2; e2.x = et[i & 15].z; e2.y = et[i & 15].w;   // (-s, s)
      s[i] = e1 * s[i] + e2 * swapv(s[i]);
    }
    perm2<LYR + 1>(s, L0, L1, lane);
  }
  // layer 3: omega-diag dropped (pure phase); perm folded into epilogue signs
}

// In-register Walsh-Hadamard stage over the 4 e-bits.
template<int M>
__device__ __forceinline__ void wht(float (&h)[16]) {
  #pragma unroll
  for (int e0 = 0; e0 < 16; ++e0) {
    if (e0 & M) continue;
    float u = h[e0], v = h[e0 | M];
    h[e0] = u + v;
    h[e0 | M] = u - v;
  }
}
template<int Q>
__device__ __forceinline__ float zfin(const float (&h)[16], int lane) {
  constexpr int aq = amask(Q);
  constexpr int mq = mmask(Q);
  float t = h[mq];
  if constexpr (aq != 0) {
    int par = __builtin_popcount(lane & aq) & 1;
    t = par ? -t : t;
  }
  return red64(t);
}

// ------------------------------------------------------- fused simulation ---
// R17: TWO rows per wave, fully unrolled (R10's confounds removed: no rolled
// loop, shared E-prefetch, static perms). Grid = 2048 waves = 2 waves/SIMD
// (grid-capped) -> launch_bounds(256,1) frees the allocator to 256 VGPRs;
// row-B work fills row-A's perm/permlane stalls (within-wave MLP).
__global__ __launch_bounds__(256, 1) void vqc_sim(const float* __restrict__ X,
                                                  const float* __restrict__ Gg,
                                                  const float* __restrict__ W,
                                                  const float* __restrict__ bias,
                                                  float* __restrict__ out) {
  __shared__ f32x2 lds[8][DIMQ];     // 64 KB: 2 slices per wave, 4 waves
  const int lane = threadIdx.x & 63;
  const int w = threadIdx.x >> 6;
  const int row0 = (blockIdx.x * 4 + w) * 2;
  f32x2* L0 = lds[2 * w + 0];
  f32x2* L1 = lds[2 * w + 1];
  const float4* gq  = (const float4*)Gg;
  const f32x2* D0   = (const f32x2*)(Gg + 256);
  const float4* Etab = (const float4*)(D0 + 1024);

  f32x2 s[32];
  float rn2[2];

  // ---- load both rows; init = x * D_phi^0; norms ----
  const float* xr = X + (size_t)row0 * DIMQ;
  #pragma unroll
  for (int r = 0; r < 2; ++r) {
    float ss = 0.f;
    #pragma unroll
    for (int e = 0; e < 16; ++e) {
      float v = xr[r * DIMQ + (e << 6) + lane];
      ss += v * v;
      s[r * 16 + e] = v * D0[(e << 6) | lane];
    }
    rn2[r] = 1.0f / red64(ss);
  }

  do_layer<0>(s, gq, Etab, L0, L1, lane);
  do_layer<1>(s, gq, Etab, L0, L1, lane);
  do_layer<2>(s, gq, Etab, L0, L1, lane);
  do_layer<3>(s, gq, Etab, L0, L1, lane);

  // ---- per row: probs -> WHT -> z -> linear head ----
  #pragma unroll
  for (int r = 0; r < 2; ++r) {
    float h[16];
    #pragma unroll
    for (int e = 0; e < 16; ++e) {
      f32x2 t = s[r * 16 + e];
      h[e] = t.x * t.x + t.y * t.y;
    }
    wht<1>(h); wht<2>(h); wht<4>(h); wht<8>(h);

    float z[10];
    z[0] = zfin<0>(h, lane);
    z[1] = zfin<1>(h, lane);
    z[2] = zfin<2>(h, lane);
    z[3] = zfin<3>(h, lane);
    z[4] = zfin<4>(h, lane);
    z[5] = zfin<5>(h, lane);
    z[6] = zfin<6>(h, lane);
    z[7] = zfin<7>(h, lane);
    z[8] = zfin<8>(h, lane);
    z[9] = zfin<9>(h, lane);

    if (lane < 16) {
      float acc = 0.f;
      #pragma unroll
      for (int q = 0; q < 10; ++q) acc += z[q] * W[lane * 10 + q];
      out[(size_t)(row0 + r) * 16 + lane] = bias[lane] + rn2[r] * acc;
    }
  }
}

extern "C" void kernel_launch(void* const* d_in, const int* in_sizes, int n_in,
                              void* d_out, int out_size, void* d_ws, size_t ws_size,
                              hipStream_t stream) {
  const float* X    = (const float*)d_in[0];
  const float* wts  = (const float*)d_in[1];
  const float* W    = (const float*)d_in[2];
  const float* bias = (const float*)d_in[3];
  float* out = (float*)d_out;
  float* Gg = (float*)d_ws;   // gq 160 + pad + D0 2048 + E 12288 floats ~= 59 KB

  hipLaunchKernelGGL(prep_g,  dim3(4),         dim3(256), 0, stream, wts, Gg);
  hipLaunchKernelGGL(vqc_sim, dim3(BATCH / 8), dim3(256), 0, stream, X, Gg, W, bias, out);
}

// Round 18
// 92.448 us; speedup vs baseline: 1.0546x; 1.0546x over previous
//
#include <hip/hip_runtime.h>
#include <stdint.h>

#define NQ 10
#define DIMQ 1024
#define BATCH 4096

typedef float f32x2 __attribute__((ext_vector_type(2)));

#if __has_builtin(__builtin_amdgcn_permlane16_swap)
#define HAS_PL16 1
#else
#define HAS_PL16 0
#endif

// Layer's 10 CNOTs composed as a GF(2)-linear index map (scatter form).
__host__ __device__ constexpr int cperm_c(int x, int r) {
  for (int q = 0; q < NQ; ++q) {
    const int c = 9 - q;
    int t = c - r; if (t < 0) t += NQ;
    x ^= ((x >> c) & 1) << t;
  }
  return x;
}
// Epilogue sign masks (layer-3 perm r=4 folded into signs).
constexpr int amask(int q) {
  int a = 0;
  for (int b = 0; b < 6; ++b) a |= ((cperm_c(1 << b, 4) >> (9 - q)) & 1) << b;
  return a;
}
constexpr int mmask(int q) {
  int m = 0;
  for (int b = 0; b < 4; ++b) m |= ((cperm_c(1 << (6 + b), 4) >> (9 - q)) & 1) << b;
  return m;
}

// ------------------------------------------------------- gate precompute ---
// Per gate: float4 (c, s, t, 0), t = tan(theta/2) for the 3-shear reg gates
// (R16-proven). E tables pre-packed float4 {c, c, -s, s} (R15-proven).
__global__ __launch_bounds__(256) void prep_g(const float* __restrict__ wts,
                                              float* __restrict__ Gg) {
  const int idx = blockIdx.x * 256 + threadIdx.x;   // grid 4 x 256 = 1024
  if (idx < 40) {
    float th = wts[idx * 3 + 1];
    ((float4*)Gg)[idx] = make_float4(cosf(0.5f * th), sinf(0.5f * th),
                                     tanf(0.25f * th), 0.f);
  }
  f32x2* D0 = (f32x2*)(Gg + 256);
  float4* E = (float4*)(D0 + 1024);     // E0, E1, E2 consecutive (1024 each)
  auto sphase = [&](int l, int i, int comp) {   // comp: 0=phi, 2=omega
    float s = 0.f;
    #pragma unroll
    for (int q = 0; q < 10; ++q) {              // wts loads are uniform
      float sg = ((i >> (9 - q)) & 1) ? 0.5f : -0.5f;
      s += sg * wts[(l * 10 + q) * 3 + comp];
    }
    return s;
  };
  float p0 = sphase(0, idx, 0);
  D0[idx] = (f32x2){cosf(p0), sinf(p0)};
  #pragma unroll
  for (int l = 0; l < 3; ++l) {
    float a = sphase(l, idx, 2) + sphase(l + 1, cperm_c(idx, l + 1), 0);
    E[l * 1024 + idx] = make_float4(cosf(a), cosf(a), -sinf(a), sinf(a));
  }
}

// ---- VALU-pipe lane shuffles ----
template<int CTRL>
__device__ __forceinline__ float dpp1(float x) {
  return __int_as_float(
      __builtin_amdgcn_update_dpp(0, __float_as_int(x), CTRL, 0xF, 0xF, true));
}
// quad_perm xor1=0xB1, xor2=0x4E, xor3=0x1B; row_half_mirror(^7)=0x141;
// row_ror:8 = 0x128 == xor8 within a 16-lane row.
template<int P>   // P = lane bit: 1 (quad_perm) or 3 (row_ror:8)
__device__ __forceinline__ float shufl(float x) {
  if constexpr (P == 0)      return dpp1<0xB1>(x);
  else if constexpr (P == 1) return dpp1<0x4E>(x);
  else if constexpr (P == 2) return dpp1<0x141>(dpp1<0x1B>(x));
  else                       return dpp1<0x128>(x);   // row_ror:8 == ^8
}

__device__ __forceinline__ f32x2 swapv(f32x2 v) {
  return __builtin_shufflevector(v, v, 1, 0);
}

// Wave sum -> uniform scalar.
__device__ __forceinline__ float red64(float v) {
  v += dpp1<0xB1>(v);
  v += dpp1<0x4E>(v);
  v += dpp1<0x141>(dpp1<0x1B>(v));   // ^4
  v += dpp1<0x128>(v);               // ^8 (row_ror:8)
#if HAS_PL16
  { auto rr = __builtin_amdgcn_permlane16_swap(__float_as_uint(v),
                                               __float_as_uint(v), false, false);
    v = __uint_as_float(rr[0]) + __uint_as_float(rr[1]); }
#else
  v += __int_as_float(__builtin_amdgcn_ds_swizzle(__float_as_int(v), 0x401F));
#endif
  auto p = __builtin_amdgcn_permlane32_swap(__float_as_uint(v),
                                            __float_as_uint(v), false, false);
  return __uint_as_float(p[0]) + __uint_as_float(p[1]);
}

// ---- REAL Givens rotations on 16 amps/lane ----
// Reg-bit gate in 3-shear (lifting) form (R16-proven).
template<int MT>   // e bits 3..0 (idx bits 9:6)
__device__ __forceinline__ void ry_reg(f32x2 (&s)[16], float t, float sn) {
  #pragma unroll
  for (int e0 = 0; e0 < 16; ++e0) {
    if (e0 & MT) continue;
    const int e1 = e0 | MT;
    s[e0] = s[e0] - t * s[e1];
    s[e1] = s[e1] + sn * s[e0];
    s[e0] = s[e0] - t * s[e1];
  }
}
template<int P>    // lane bits via single-DPP patterns (^2, ^8)
__device__ __forceinline__ void ry_dpp(f32x2 (&s)[16], float2 cs, int lane) {
  const float c = cs.x;
  const float ss = ((lane >> P) & 1) ? cs.y : -cs.y;
  #pragma unroll
  for (int e = 0; e < 16; ++e) {
    f32x2 o;
    o.x = shufl<P>(s[e].x);
    o.y = shufl<P>(s[e].y);
    s[e] = c * s[e] + ss * o;
  }
}
// R18: generic ds_swizzle xor gate (DS crossbar — bankless, no LDS memory).
// Extends R16's proven ^4 offload: 2 DS + 2 VALU/elem vs 4-5 VALU/elem.
// BitMode offset = (xor_mask << 10) | 0x1F. Valid for lane bits 0..4.
template<int B>    // lane bit, 0..4
__device__ __forceinline__ void ry_ds(f32x2 (&s)[16], float2 cs, int lane) {
  constexpr int OFF = ((1 << B) << 10) | 0x1F;
  const float c = cs.x;
  const float ss = ((lane >> B) & 1) ? cs.y : -cs.y;
  #pragma unroll
  for (int e = 0; e < 16; ++e) {
    f32x2 o;
    o.x = __int_as_float(__builtin_amdgcn_ds_swizzle(__float_as_int(s[e].x), OFF));
    o.y = __int_as_float(__builtin_amdgcn_ds_swizzle(__float_as_int(s[e].y), OFF));
    s[e] = c * s[e] + ss * o;
  }
}
// lane bit 5 (xor32): select-free permlane32_swap (R15-proven; only option —
// ds_swizzle is within-32-lane).
__device__ __forceinline__ void ry5(f32x2 (&s)[16], float2 cs, int lane) {
  const int L = lane >> 5;
  const float c = cs.x;
  const float a0 = L ? cs.y : 0.f;     // coeff on rr[0] (lo half value)
  const float a1 = L ? 0.f : -cs.y;    // coeff on rr[1] (hi half value)
  #pragma unroll
  for (int e = 0; e < 16; ++e) {
    auto rr = __builtin_amdgcn_permlane32_swap(__float_as_uint(s[e].x),
                                               __float_as_uint(s[e].x), false, false);
    auto ri = __builtin_amdgcn_permlane32_swap(__float_as_uint(s[e].y),
                                               __float_as_uint(s[e].y), false, false);
    f32x2 o0, o1;
    o0.x = __uint_as_float(rr[0]); o0.y = __uint_as_float(ri[0]);
    o1.x = __uint_as_float(rr[1]); o1.y = __uint_as_float(ri[1]);
    s[e] = c * s[e] + a0 * o0 + a1 * o1;
  }
}

// CNOT permutation via private per-wave LDS slice (same-wave DS in-order,
// no barrier).
template<int R>
__device__ __forceinline__ void perm_state(f32x2 (&s)[16], f32x2* __restrict__ L,
                                           int lane) {
  constexpr int K0=cperm_c(1,R),  K1=cperm_c(2,R),  K2=cperm_c(4,R),
                K3=cperm_c(8,R),  K4=cperm_c(16,R), K5=cperm_c(32,R),
                C6=cperm_c(64,R), C7=cperm_c(128,R),
                C8=cperm_c(256,R),C9=cperm_c(512,R);
  const int yl = ((lane & 1)  ? K0 : 0) ^ ((lane & 2)  ? K1 : 0) ^
                 ((lane & 4)  ? K2 : 0) ^ ((lane & 8)  ? K3 : 0) ^
                 ((lane & 16) ? K4 : 0) ^ ((lane & 32) ? K5 : 0);
  #pragma unroll
  for (int e = 0; e < 16; ++e) {
    const int ye = ((e & 1) ? C6 : 0) ^ ((e & 2) ? C7 : 0) ^
                   ((e & 4) ? C8 : 0) ^ ((e & 8) ? C9 : 0);
    L[yl ^ ye] = s[e];
  }
  #pragma unroll
  for (int e = 0; e < 16; ++e) s[e] = L[(e << 6) | lane];
}

template<int LYR>
__device__ __forceinline__ void do_layer(f32x2 (&s)[16],
                                         const float4* __restrict__ gq,
                                         const float4* __restrict__ Etab,
                                         f32x2* __restrict__ L, int lane) {
  // E-prefetch first: the 10-gate VALU sequence below hides the L2 latency.
  float4 et[16];
  if constexpr (LYR < 3) {
    const float4* El = Etab + LYR * 1024;
    #pragma unroll
    for (int e = 0; e < 16; ++e) et[e] = El[(e << 6) | lane];
  }
  const float4* G = gq + LYR * 10;
  ry_reg<8>(s, G[0].z, G[0].y);          // q0 -> bit9 (3-shear)
  ry_reg<4>(s, G[1].z, G[1].y);          // q1 -> bit8
  ry_reg<2>(s, G[2].z, G[2].y);          // q2 -> bit7
  ry_reg<1>(s, G[3].z, G[3].y);          // q3 -> bit6
  ry5     (s, make_float2(G[4].x, G[4].y), lane);  // q4 -> bit5 (permlane32)
  ry_ds<4>(s, make_float2(G[5].x, G[5].y), lane);  // q5 -> bit4 (ds_swizzle)
  ry_dpp<3>(s, make_float2(G[6].x, G[6].y), lane); // q6 -> bit3 (row_ror:8)
  ry_ds<2>(s, make_float2(G[7].x, G[7].y), lane);  // q7 -> bit2 (ds_swizzle)
  ry_dpp<1>(s, make_float2(G[8].x, G[8].y), lane); // q8 -> bit1 (DPP)
  ry_ds<0>(s, make_float2(G[9].x, G[9].y), lane);  // q9 -> bit0 (ds_swizzle)
  if constexpr (LYR < 3) {
    #pragma unroll
    for (int e = 0; e < 16; ++e) {       // merged diag: 2 packed ops
      f32x2 e1; e1.x = et[e].x; e1.y = et[e].y;   // (c, c)
      f32x2 e2; e2.x = et[e].z; e2.y = et[e].w;   // (-s, s)
      s[e] = e1 * s[e] + e2 * swapv(s[e]);
    }
    perm_state<LYR + 1>(s, L, lane);
  }
  // layer 3: omega-diag dropped (pure phase); perm folded into epilogue signs
}

// In-register Walsh-Hadamard stage over the 4 e-bits.
template<int M>
__device__ __forceinline__ void wht(float (&h)[16]) {
  #pragma unroll
  for (int e0 = 0; e0 < 16; ++e0) {
    if (e0 & M) continue;
    float u = h[e0], v = h[e0 | M];
    h[e0] = u + v;
    h[e0 | M] = u - v;
  }
}
template<int Q>
__device__ __forceinline__ float zfin(const float (&h)[16], int lane) {
  constexpr int aq = amask(Q);
  constexpr int mq = mmask(Q);
  float t = h[mq];
  if constexpr (aq != 0) {
    int par = __builtin_popcount(lane & aq) & 1;
    t = par ? -t : t;
  }
  return red64(t);
}

// ------------------------------------------------------- fused simulation ---
// R16 structure (proven best, 94.6 total): one row per wave, 16 amps/lane,
// unrolled layers, 4 waves/SIMD, zero __syncthreads, E-prefetch, packed
// E-pairs, 3-shear reg gates. R18: extend the R16 pipe-rebalance — lane
// gates ^0 and ^4 (prev. DPP/permlane16, 4-5 VALU/elem) moved to the
// near-idle DS crossbar (2 DS + 2 VALU/elem). DS/layer ~128 ops ~ balanced
// against ~430 VALU ops.
__global__ __launch_bounds__(256, 2) void vqc_sim(const float* __restrict__ X,
                                                  const float* __restrict__ Gg,
                                                  const float* __restrict__ W,
                                                  const float* __restrict__ bias,
                                                  float* __restrict__ out) {
  __shared__ f32x2 lds[4][DIMQ];     // 32 KB perm slices (per-wave private)
  const int lane = threadIdx.x & 63;
  const int w = threadIdx.x >> 6;
  const int row = blockIdx.x * 4 + w;
  f32x2* L = lds[w];
  const float4* gq  = (const float4*)Gg;
  const f32x2* D0   = (const f32x2*)(Gg + 256);
  const float4* Etab = (const float4*)(D0 + 1024);

  f32x2 s[16];

  // ---- load; init state = x * D_phi^0 (first diagonal on real input) ----
  const float* xr = X + (size_t)row * DIMQ;
  float ss = 0.f;
  #pragma unroll
  for (int e = 0; e < 16; ++e) {
    float v = xr[(e << 6) | lane];
    ss += v * v;
    s[e] = v * D0[(e << 6) | lane];
  }
  const float rn2 = 1.0f / red64(ss);   // uniform probability scale

  do_layer<0>(s, gq, Etab, L, lane);
  do_layer<1>(s, gq, Etab, L, lane);
  do_layer<2>(s, gq, Etab, L, lane);
  do_layer<3>(s, gq, Etab, L, lane);

  // ---- probs -> z via WHT (layer-3 perm r=4 folded into signs) ----
  float h[16];
  #pragma unroll
  for (int e = 0; e < 16; ++e) h[e] = s[e].x * s[e].x + s[e].y * s[e].y;
  wht<1>(h); wht<2>(h); wht<4>(h); wht<8>(h);

  float z[10];
  z[0] = zfin<0>(h, lane);
  z[1] = zfin<1>(h, lane);
  z[2] = zfin<2>(h, lane);
  z[3] = zfin<3>(h, lane);
  z[4] = zfin<4>(h, lane);
  z[5] = zfin<5>(h, lane);
  z[6] = zfin<6>(h, lane);
  z[7] = zfin<7>(h, lane);
  z[8] = zfin<8>(h, lane);
  z[9] = zfin<9>(h, lane);

  // ---- linear head (rn2 applied once) ----
  if (lane < 16) {
    float acc = 0.f;
    #pragma unroll
    for (int q = 0; q < 10; ++q) acc += z[q] * W[lane * 10 + q];
    out[(size_t)row * 16 + lane] = bias[lane] + rn2 * acc;
  }
}

extern "C" void kernel_launch(void* const* d_in, const int* in_sizes, int n_in,
                              void* d_out, int out_size, void* d_ws, size_t ws_size,
                              hipStream_t stream) {
  const float* X    = (const float*)d_in[0];
  const float* wts  = (const float*)d_in[1];
  const float* W    = (const float*)d_in[2];
  const float* bias = (const float*)d_in[3];
  float* out = (float*)d_out;
  float* Gg = (float*)d_ws;   // gq 160 + pad + D0 2048 + E 12288 floats ~= 59 KB

  hipLaunchKernelGGL(prep_g,  dim3(4),         dim3(256), 0, stream, wts, Gg);
  hipLaunchKernelGGL(vqc_sim, dim3(BATCH / 4), dim3(256), 0, stream, X, Gg, W, bias, out);
}